// Round 7
// baseline (327.092 us; speedup 1.0000x reference)
//
#include <hip/hip_runtime.h>

typedef unsigned int u32;
typedef unsigned short u16;
typedef unsigned char u8;
typedef long i64;
typedef __attribute__((ext_vector_type(8))) short short8;
typedef __attribute__((ext_vector_type(4))) float f32x4;

#define MAXBIN 1024   // bins of 128 dsts; N=100k -> 782 bins
#define SORT_TPB 1024 // threads/block for hist+scatter: 16 waves/block for latency hiding
#define BINSLACK 2048 // per-bin csr padding slack (>= 128 dsts x max 8 pad each)

__device__ inline u16 f2bf(float f) {
    u32 u = __builtin_bit_cast(u32, f);
    u32 r = (u + 0x7fffu + ((u >> 16) & 1u)) >> 16;  // RTNE
    return (u16)r;
}

// MFMA-as-summation: C[m][n] = sum_k A[m][k] * B[k][n], B[k][n] = 1.0 iff n == (k&7).
// A fragment = gathered fp8 rows (lane&15 = A-row m, lane>>4 = k-group/edge slot,
// 8 consecutive bytes per lane). C[m][n] += sum over slots of byte n of row m.
__device__ inline f32x4 mfma_fp8(uint2 a, uint2 b, f32x4 c) {
    return __builtin_amdgcn_mfma_f32_16x16x32_fp8_fp8(
        __builtin_bit_cast(i64, a), __builtin_bit_cast(i64, b), c, 0, 0, 0);
}

// Output-feature permutation induced by the MFMA C layout. Position p in the stored
// row holds true feature pi(p); pi is baked into wt2/wt3 k-dim (exact, free).
__device__ inline int permP(int p) {
    return ((p >> 5) << 5) + ((p & 3) << 3) + ((p >> 2) & 7);
}

// ---------- CSR build: two-level binned counting sort, LDS-resident counters ----
// R1 lesson (counters): direct random 4B scatter = 106MB WRITE_SIZE (16x line
// write-amplification), 129us. Binned scatter keeps ~32-64B write runs.
// R2: 256 blocks x 1024 threads fixed the 3.7%-occupancy latency bound.
// R4/R5: csr PADDED per node (self-loop folded in, sentinel N fills), mask-free agg.
// R6: pad mult-8. R7: agg kernels issue the whole node as ONE batch (latency-bound
// fix): all csr loads -> all gathers -> all MFMAs, wave-uniform degree class.
__global__ __launch_bounds__(SORT_TPB) void k_bhist(const int* __restrict__ ei, int E, int W,
                                                    int* __restrict__ binTot, int NBIN) {
    __shared__ int h[MAXBIN];
    int tid = threadIdx.x;
    for (int i = tid; i < NBIN; i += SORT_TPB) h[i] = 0;
    __syncthreads();
    int s = blockIdx.x * W, e = min(E, s + W);
    for (int j = s + tid; j < e; j += SORT_TPB) atomicAdd(&h[ei[E + j] >> 7], 1);
    __syncthreads();
    for (int i = tid; i < NBIN; i += SORT_TPB) {
        int v = h[i];
        if (v) atomicAdd(&binTot[i], v);
    }
}

__global__ void k_bscan(const int* __restrict__ binTot, int NBIN,
                        int* __restrict__ binStart, int* __restrict__ binCur) {
    __shared__ int wsum[4];
    int t = threadIdx.x;
    int base = t * 4;
    int v0 = (base + 0 < NBIN) ? binTot[base + 0] : 0;
    int v1 = (base + 1 < NBIN) ? binTot[base + 1] : 0;
    int v2 = (base + 2 < NBIN) ? binTot[base + 2] : 0;
    int v3 = (base + 3 < NBIN) ? binTot[base + 3] : 0;
    int s = v0 + v1 + v2 + v3;
    int lane = t & 63, wv = t >> 6;
    int isc = s;
    for (int d = 1; d < 64; d <<= 1) { int o = __shfl_up(isc, d, 64); if (lane >= d) isc += o; }
    if (lane == 63) wsum[wv] = isc;
    __syncthreads();
    int woff = 0;
    for (int w = 0; w < wv; w++) woff += wsum[w];
    int run = woff + isc - s;
    if (base + 0 < NBIN) { binStart[base + 0] = run; binCur[base + 0] = run; } run += v0;
    if (base + 1 < NBIN) { binStart[base + 1] = run; binCur[base + 1] = run; } run += v1;
    if (base + 2 < NBIN) { binStart[base + 2] = run; binCur[base + 2] = run; } run += v2;
    if (base + 3 < NBIN) { binStart[base + 3] = run; binCur[base + 3] = run; }
    if (t == 255) binStart[NBIN] = wsum[0] + wsum[1] + wsum[2] + wsum[3];
}

__global__ __launch_bounds__(SORT_TPB) void k_bscatter(const int* __restrict__ ei, int E, int W,
                                                       int* __restrict__ binCur,
                                                       u32* __restrict__ binned, int NBIN) {
    __shared__ int lh[MAXBIN];
    __shared__ int lb[MAXBIN];
    int tid = threadIdx.x;
    for (int i = tid; i < NBIN; i += SORT_TPB) lh[i] = 0;
    __syncthreads();
    int s = blockIdx.x * W, e = min(E, s + W);
    for (int j = s + tid; j < e; j += SORT_TPB) atomicAdd(&lh[ei[E + j] >> 7], 1);
    __syncthreads();
    for (int i = tid; i < NBIN; i += SORT_TPB) {
        int h = lh[i];
        lb[i] = h ? atomicAdd(&binCur[i], h) : 0;
    }
    __syncthreads();
    for (int i = tid; i < NBIN; i += SORT_TPB) lh[i] = 0;
    __syncthreads();
    for (int j = s + tid; j < e; j += SORT_TPB) {
        int d = ei[E + j];
        int b = d >> 7;
        int r = atomicAdd(&lh[b], 1);
        binned[lb[b] + r] = ((u32)ei[j] << 7) | (u32)(d & 127);
    }
}

// Padded CSR: per-dst slots pc = (c+1 self) rounded up to 8 = (c+8)&~7.
// Bin b's padded region starts at binStart[b] + BINSLACK*b (fixed slack, no extra
// global scan); whole region sentinel-filled (N), then self + real edges overwrite.
// offs[d] = start, ends[d] = start + pc  (exact mult-8 range, no gap reads).
__global__ __launch_bounds__(256) void k_bcsr(const u32* __restrict__ binned,
                                              const int* __restrict__ binStart,
                                              int N, int E, int* __restrict__ offs,
                                              int* __restrict__ ends,
                                              float* __restrict__ dinv,
                                              int* __restrict__ csr, int NBIN) {
    __shared__ int cnt[128];
    __shared__ int off[128];
    __shared__ int tot;
    int b = blockIdx.x;
    int tid = threadIdx.x;
    int dLo = b << 7;
    int nd = min(128, N - dLo);
    int e0 = binStart[b], e1 = binStart[b + 1];
    int pbase = e0 + b * BINSLACK;
    int pend = e1 + (b + 1) * BINSLACK;
    if (tid < 128) cnt[tid] = 0;
    __syncthreads();
    for (int j = e0 + tid; j < e1; j += 256) atomicAdd(&cnt[binned[j] & 127u], 1);
    __syncthreads();
    int c = (tid < 128) ? cnt[tid] : 0;
    int pc = (tid < 128) ? ((c + 8) & ~7) : 0;  // (c+1 self) rounded up to 8
    int lane = tid & 63;
    int isc = pc;
    for (int d = 1; d < 64; d <<= 1) { int o = __shfl_up(isc, d, 64); if (lane >= d) isc += o; }
    if (tid == 63) tot = isc;
    __syncthreads();
    int add = (tid >= 64 && tid < 128) ? tot : 0;
    if (tid < 128) off[tid] = add + isc - pc;
    // sentinel-fill entire padded bin region (covers all pads incl. unused slack)
    for (int j = pbase + tid; j < pend; j += 256) csr[j] = N;
    __syncthreads();
    if (tid < nd) {
        offs[dLo + tid] = pbase + off[tid];
        ends[dLo + tid] = pbase + off[tid] + pc;
        dinv[dLo + tid] = rsqrtf((float)(c + 1));
        csr[pbase + off[tid] + c] = dLo + tid;  // self-loop entry
    }
    if (tid < 128) cnt[tid] = 0;
    __syncthreads();
    for (int j = e0 + tid; j < e1; j += 256) {
        u32 v = binned[j];
        int d7 = (int)(v & 127u);
        int r = atomicAdd(&cnt[d7], 1);
        csr[pbase + off[d7] + r] = (int)(v >> 7);
    }
}

// ---------- fused weight converts (W[K][M] row-major -> Wt[M][K] bf16) ----------
// wt2/wt3 k-dim permuted by pi (agg128 stores feature pi(p) at position p).
__global__ void k_wtall(const float* __restrict__ W1, const float* __restrict__ W2,
                        const float* __restrict__ W3, u16* __restrict__ wt1,
                        u16* __restrict__ wt2, u16* __restrict__ wt3) {
    int idx = blockIdx.x * 256 + threadIdx.x;
    if (idx < 16384) {
        int k = idx >> 7, m = idx & 127;
        wt1[m * 128 + k] = f2bf(W1[idx]);
    } else if (idx < 32768) {
        int i = idx - 16384, p = i >> 7, m = i & 127;
        wt2[m * 128 + p] = f2bf(W2[permP(p) * 128 + m]);
    } else if (idx < 40960) {
        int i = idx - 32768, p = i >> 6, m = i & 63;
        wt3[m * 128 + p] = f2bf(W3[permP(p) * 64 + m]);
    }
}

// ---------- GEMM: g8 = fp8((x @ W) * dinv[row] * 16); also zeroes sentinel row N --
template <int M, bool F32IN>
__global__ __launch_bounds__(256) void k_gemm(const void* __restrict__ xin,
                                              const u16* __restrict__ wt,
                                              const float* __restrict__ dinv,
                                              u8* __restrict__ g8, int N) {
    constexpr int K = 128;
    constexpr int LDK = 136;
    __shared__ u16 lwt[M * LDK];
    int tid = threadIdx.x;
    if (blockIdx.x == 0 && tid < M / 16)  // keep sentinel row zero for padded agg
        *(uint4*)(g8 + (size_t)N * M + (size_t)tid * 16) = make_uint4(0u, 0u, 0u, 0u);
    const uint4* wsrc = (const uint4*)wt;
#pragma unroll
    for (int c = tid; c < M * K / 8; c += 256) {
        int row = c >> 4, kc = c & 15;
        *(uint4*)&lwt[row * LDK + kc * 8] = wsrc[c];
    }
    __syncthreads();
    int lane = tid & 63, wv = tid >> 6;
    int node = blockIdx.x * 64 + wv * 16 + (lane & 15);
    int nodec = min(node, N - 1);
    int kr = (lane >> 4) * 8;
    f32x4 acc[M / 16];
#pragma unroll
    for (int t = 0; t < M / 16; t++) acc[t] = (f32x4){0.f, 0.f, 0.f, 0.f};
#pragma unroll
    for (int ks = 0; ks < 4; ks++) {
        short8 bfr;
        if (F32IN) {
            const float* xr = (const float*)xin + (size_t)nodec * K + ks * 32 + kr;
            float4 fa = *(const float4*)xr;
            float4 fb = *(const float4*)(xr + 4);
            bfr = (short8){(short)f2bf(fa.x), (short)f2bf(fa.y), (short)f2bf(fa.z),
                           (short)f2bf(fa.w), (short)f2bf(fb.x), (short)f2bf(fb.y),
                           (short)f2bf(fb.z), (short)f2bf(fb.w)};
        } else {
            bfr = *(const short8*)((const u16*)xin + (size_t)nodec * K + ks * 32 + kr);
        }
#pragma unroll
        for (int t = 0; t < M / 16; t++) {
            short8 afr = *(const short8*)&lwt[(t * 16 + (lane & 15)) * LDK + ks * 32 + kr];
            acc[t] = __builtin_amdgcn_mfma_f32_16x16x32_bf16(afr, bfr, acc[t], 0, 0, 0);
        }
    }
    if (node < N) {
        float dv16 = dinv[node] * 16.0f;
        int r0 = (lane >> 4) * 4;
#pragma unroll
        for (int t = 0; t < M / 16; t++) {
            u32 w = __builtin_amdgcn_cvt_pk_fp8_f32(acc[t][0] * dv16, acc[t][1] * dv16, 0, false);
            w = __builtin_amdgcn_cvt_pk_fp8_f32(acc[t][2] * dv16, acc[t][3] * dv16, w, true);
            *(u32*)(g8 + (size_t)node * M + t * 16 + r0) = w;
        }
    }
}

// ---------- aggregation via MFMA, single-batch per node ----------
// R6 counters: k_agg64 unchanged at issued-work reduction -> latency-bound on the
// per-node csr->gather->mfma chain, repeated serially per window. R7: issue the
// WHOLE node as one batch (rem <= 32 after rare 32-peel): all csr loads in
// flight, then all gathers, then MFMAs. mu is wave-uniform -> s_cbranch only.
__global__ __launch_bounds__(256) void k_agg128(const u8* __restrict__ g8,
                                                const int* __restrict__ offs,
                                                const int* __restrict__ ends,
                                                const int* __restrict__ csr,
                                                const float* __restrict__ dinv,
                                                const float* __restrict__ bias,
                                                u16* __restrict__ hout, int N) {
    int wid = (blockIdx.x * 256 + threadIdx.x) >> 6;  // one wave per node
    if (wid >= N) return;
    int lane = threadIdx.x & 63;
    int q = lane >> 4;   // edge slot within each MFMA
    int f = lane & 15;   // A-row: feature chunk (bytes f*8..f*8+7 of each row)
    int s = offs[wid], e = ends[wid];
    uint2 bsel;
    bsel.x = (f < 4) ? (0x38u << (8 * f)) : 0u;               // fp8 e4m3 1.0 = 0x38
    bsel.y = (f >= 4 && f < 8) ? (0x38u << (8 * (f - 4))) : 0u;
    const u8* gf = g8 + f * 8;
    f32x4 ac0 = {0.f, 0.f, 0.f, 0.f}, ac1 = ac0, ac2 = ac0, ac3 = ac0;
    int j = s;
    // rare big nodes: peel 32-slot blocks until remainder <= 32 (wave-uniform)
    for (; e - j > 32; j += 32) {
        int i0 = csr[j + q],      i1 = csr[j + 4 + q];
        int i2 = csr[j + 8 + q],  i3 = csr[j + 12 + q];
        int i4 = csr[j + 16 + q], i5 = csr[j + 20 + q];
        int i6 = csr[j + 24 + q], i7 = csr[j + 28 + q];
        uint2 g0 = *(const uint2*)(gf + ((u32)i0 << 7));
        uint2 g1 = *(const uint2*)(gf + ((u32)i1 << 7));
        uint2 g2 = *(const uint2*)(gf + ((u32)i2 << 7));
        uint2 g3 = *(const uint2*)(gf + ((u32)i3 << 7));
        uint2 g4 = *(const uint2*)(gf + ((u32)i4 << 7));
        uint2 g5 = *(const uint2*)(gf + ((u32)i5 << 7));
        uint2 g6 = *(const uint2*)(gf + ((u32)i6 << 7));
        uint2 g7 = *(const uint2*)(gf + ((u32)i7 << 7));
        ac0 = mfma_fp8(g0, bsel, ac0);
        ac1 = mfma_fp8(g1, bsel, ac1);
        ac2 = mfma_fp8(g2, bsel, ac2);
        ac3 = mfma_fp8(g3, bsel, ac3);
        ac0 = mfma_fp8(g4, bsel, ac0);
        ac1 = mfma_fp8(g5, bsel, ac1);
        ac2 = mfma_fp8(g6, bsel, ac2);
        ac3 = mfma_fp8(g7, bsel, ac3);
    }
    // batched finish: remainder in {8,16,24,32} -> mu in 1..4
    int mu = (e - j) >> 3;
    int i0 = csr[j + q], i1 = csr[j + 4 + q];
    int i2 = 0, i3 = 0, i4 = 0, i5 = 0, i6 = 0, i7 = 0;
    if (mu > 1) { i2 = csr[j + 8 + q];  i3 = csr[j + 12 + q]; }
    if (mu > 2) { i4 = csr[j + 16 + q]; i5 = csr[j + 20 + q]; }
    if (mu > 3) { i6 = csr[j + 24 + q]; i7 = csr[j + 28 + q]; }
    uint2 g0 = *(const uint2*)(gf + ((u32)i0 << 7));
    uint2 g1 = *(const uint2*)(gf + ((u32)i1 << 7));
    uint2 g2 = make_uint2(0u, 0u), g3 = g2, g4 = g2, g5 = g2, g6 = g2, g7 = g2;
    if (mu > 1) { g2 = *(const uint2*)(gf + ((u32)i2 << 7)); g3 = *(const uint2*)(gf + ((u32)i3 << 7)); }
    if (mu > 2) { g4 = *(const uint2*)(gf + ((u32)i4 << 7)); g5 = *(const uint2*)(gf + ((u32)i5 << 7)); }
    if (mu > 3) { g6 = *(const uint2*)(gf + ((u32)i6 << 7)); g7 = *(const uint2*)(gf + ((u32)i7 << 7)); }
    ac0 = mfma_fp8(g0, bsel, ac0);
    ac1 = mfma_fp8(g1, bsel, ac1);
    if (mu > 1) { ac2 = mfma_fp8(g2, bsel, ac2); ac3 = mfma_fp8(g3, bsel, ac3); }
    if (mu > 2) { ac0 = mfma_fp8(g4, bsel, ac0); ac1 = mfma_fp8(g5, bsel, ac1); }
    if (mu > 3) { ac2 = mfma_fp8(g6, bsel, ac2); ac3 = mfma_fp8(g7, bsel, ac3); }
    f32x4 a = (ac0 + ac1) + (ac2 + ac3);
    // C layout: col = lane&15 (= n, valid <8), row = (lane>>4)*4 + r (= feature chunk)
    int jn = lane & 15, fq = lane >> 4;
    if (jn < 8) {
        float sc = dinv[wid] * 0.0625f;
        u32 o0, o1;
        {
            float v0 = fmaxf(fmaf(a[0], sc, bias[(4 * fq + 0) * 8 + jn]), 0.f);
            float v1 = fmaxf(fmaf(a[1], sc, bias[(4 * fq + 1) * 8 + jn]), 0.f);
            o0 = (u32)f2bf(v0) | ((u32)f2bf(v1) << 16);
        }
        {
            float v2 = fmaxf(fmaf(a[2], sc, bias[(4 * fq + 2) * 8 + jn]), 0.f);
            float v3 = fmaxf(fmaf(a[3], sc, bias[(4 * fq + 3) * 8 + jn]), 0.f);
            o1 = (u32)f2bf(v2) | ((u32)f2bf(v3) << 16);
        }
        // permuted store: position p = fq*32 + jn*4 + r holds feature (4fq+r)*8+jn
        *(uint2*)&hout[(size_t)wid * 128 + fq * 32 + jn * 4] = make_uint2(o0, o1);
    }
}

// ---------- layer-3 aggregation + log_softmax (F=64), full-lane MFMA, batched ----
// A-rows 8-15 carry a SECOND edge half-set of the same node: 8 edges/MFMA.
// R7: same single-batch issue structure; shfl_xor(32) combines the halves.
__global__ __launch_bounds__(256) void k_agg64(const u8* __restrict__ g8,
                                               const int* __restrict__ offs,
                                               const int* __restrict__ ends,
                                               const int* __restrict__ csr,
                                               const float* __restrict__ dinv,
                                               const float* __restrict__ bias,
                                               float* __restrict__ out, int N) {
    __shared__ float sm[4][64];
    int wid = (blockIdx.x * 256 + threadIdx.x) >> 6;
    if (wid >= N) return;
    int lane = threadIdx.x & 63;
    int wv = (int)(threadIdx.x >> 6);
    int q = lane >> 4;
    int f = lane & 15;
    int qq = q + ((f >> 3) << 2);  // edge slot 0..7 within each 8-group
    int s = offs[wid], e = ends[wid];
    uint2 bsel;
    bsel.x = (f < 4) ? (0x38u << (8 * f)) : 0u;
    bsel.y = (f >= 4 && f < 8) ? (0x38u << (8 * (f - 4))) : 0u;
    const u8* gf = g8 + (f & 7) * 8;
    f32x4 ac0 = {0.f, 0.f, 0.f, 0.f}, ac1 = ac0, ac2 = ac0, ac3 = ac0;
    int j = s;
    // rare big nodes: peel 32-slot blocks (wave-uniform)
    for (; e - j > 32; j += 32) {
        int i0 = csr[j + qq], i1 = csr[j + 8 + qq];
        int i2 = csr[j + 16 + qq], i3 = csr[j + 24 + qq];
        uint2 g0 = *(const uint2*)(gf + ((u32)i0 << 6));
        uint2 g1 = *(const uint2*)(gf + ((u32)i1 << 6));
        uint2 g2 = *(const uint2*)(gf + ((u32)i2 << 6));
        uint2 g3 = *(const uint2*)(gf + ((u32)i3 << 6));
        ac0 = mfma_fp8(g0, bsel, ac0);
        ac1 = mfma_fp8(g1, bsel, ac1);
        ac2 = mfma_fp8(g2, bsel, ac2);
        ac3 = mfma_fp8(g3, bsel, ac3);
    }
    // batched finish: remainder in {8,16,24,32} -> mu in 1..4
    int mu = (e - j) >> 3;
    int i0 = csr[j + qq];
    int i1 = 0, i2 = 0, i3 = 0;
    if (mu > 1) i1 = csr[j + 8 + qq];
    if (mu > 2) i2 = csr[j + 16 + qq];
    if (mu > 3) i3 = csr[j + 24 + qq];
    uint2 g0 = *(const uint2*)(gf + ((u32)i0 << 6));
    uint2 g1 = make_uint2(0u, 0u), g2 = g1, g3 = g1;
    if (mu > 1) g1 = *(const uint2*)(gf + ((u32)i1 << 6));
    if (mu > 2) g2 = *(const uint2*)(gf + ((u32)i2 << 6));
    if (mu > 3) g3 = *(const uint2*)(gf + ((u32)i3 << 6));
    ac0 = mfma_fp8(g0, bsel, ac0);
    if (mu > 1) ac1 = mfma_fp8(g1, bsel, ac1);
    if (mu > 2) ac2 = mfma_fp8(g2, bsel, ac2);
    if (mu > 3) ac3 = mfma_fp8(g3, bsel, ac3);
    f32x4 a = (ac0 + ac1) + (ac2 + ac3);
#pragma unroll
    for (int r = 0; r < 4; r++) a[r] += __shfl_xor(a[r], 32, 64);
    int jn = lane & 15, fq = lane >> 4;
    bool act = (jn < 8) && (fq < 2);  // lanes 0-31 hold combined chunks 0-7
    if (act) {
        float sc = dinv[wid] * 0.0625f;
        float v0 = fmaf(a[0], sc, bias[(4 * fq + 0) * 8 + jn]);
        float v1 = fmaf(a[1], sc, bias[(4 * fq + 1) * 8 + jn]);
        float v2 = fmaf(a[2], sc, bias[(4 * fq + 2) * 8 + jn]);
        float v3 = fmaf(a[3], sc, bias[(4 * fq + 3) * 8 + jn]);
        float m = fmaxf(fmaxf(v0, v1), fmaxf(v2, v3));
        m = fmaxf(m, __shfl_xor(m, 1, 64));
        m = fmaxf(m, __shfl_xor(m, 2, 64));
        m = fmaxf(m, __shfl_xor(m, 4, 64));
        m = fmaxf(m, __shfl_xor(m, 16, 64));
        float ss = __expf(v0 - m) + __expf(v1 - m) + __expf(v2 - m) + __expf(v3 - m);
        ss += __shfl_xor(ss, 1, 64);
        ss += __shfl_xor(ss, 2, 64);
        ss += __shfl_xor(ss, 4, 64);
        ss += __shfl_xor(ss, 16, 64);
        float lg = m + __logf(ss);
        sm[wv][(4 * fq + 0) * 8 + jn] = v0 - lg;
        sm[wv][(4 * fq + 1) * 8 + jn] = v1 - lg;
        sm[wv][(4 * fq + 2) * 8 + jn] = v2 - lg;
        sm[wv][(4 * fq + 3) * 8 + jn] = v3 - lg;
    }
    // same-wave LDS bounce to standard order (compiler inserts lgkmcnt wait)
    if (lane < 16) {
        float4 ov = *(float4*)&sm[wv][lane * 4];
        *(float4*)&out[(size_t)wid * 64 + lane * 4] = ov;
    }
}

extern "C" void kernel_launch(void* const* d_in, const int* in_sizes, int n_in,
                              void* d_out, int out_size, void* d_ws, size_t ws_size,
                              hipStream_t stream) {
    const float* x  = (const float*)d_in[0];
    const int*   ei = (const int*)d_in[1];
    const float* W1 = (const float*)d_in[2];
    const float* b1 = (const float*)d_in[3];
    const float* W2 = (const float*)d_in[4];
    const float* b2 = (const float*)d_in[5];
    const float* W3 = (const float*)d_in[6];
    const float* b3 = (const float*)d_in[7];
    const int N = in_sizes[0] / 128;
    const int E = in_sizes[1] / 2;
    const int NBIN = (N + 127) >> 7;  // bins of 128 dsts

    char* ws = (char*)d_ws;
    size_t o = 0;
    auto alloc = [&](size_t bytes) -> char* {
        char* p = ws + o;
        o += (bytes + 255) & ~(size_t)255;
        return p;
    };
    int*   binTot = (int*)alloc((size_t)MAXBIN * 4);
    int*   binSt  = (int*)alloc((size_t)(MAXBIN + 1) * 4);
    int*   binCur = (int*)alloc((size_t)MAXBIN * 4);
    float* dinv   = (float*)alloc((size_t)N * 4);
    int*   offs   = (int*)alloc((size_t)N * 4);
    int*   endsA  = (int*)alloc((size_t)N * 4);
    int*   csr    = (int*)alloc(((size_t)E + (size_t)NBIN * BINSLACK + 64) * 4);
    u16*   wt1    = (u16*)alloc(128 * 128 * 2);
    u16*   wt2    = (u16*)alloc(128 * 128 * 2);
    u16*   wt3    = (u16*)alloc(64 * 128 * 2);
    u8*    g8     = (u8*)alloc(((size_t)N + 1) * 128);  // +1: zero sentinel row
    u16*   hbuf   = (u16*)alloc((size_t)N * 128 * 2);
    u32*   binned = (u32*)hbuf;  // lifetime-disjoint alias: dead before first agg write
    float* outp   = (float*)d_out;

    hipMemsetAsync(binTot, 0, (size_t)MAXBIN * 4, stream);
    int W256 = (E + 255) / 256;  // edges per block at 256 blocks
    k_bhist<<<256, SORT_TPB, 0, stream>>>(ei, E, W256, binTot, NBIN);
    k_bscan<<<1, 256, 0, stream>>>(binTot, NBIN, binSt, binCur);
    k_bscatter<<<256, SORT_TPB, 0, stream>>>(ei, E, W256, binCur, binned, NBIN);
    k_bcsr<<<NBIN, 256, 0, stream>>>(binned, binSt, N, E, offs, endsA, dinv, csr, NBIN);
    k_wtall<<<(40960 + 255) / 256, 256, 0, stream>>>(W1, W2, W3, wt1, wt2, wt3);

    int gG = (N + 63) / 64;                       // GEMM: 64 nodes/block
    int gA = (int)(((size_t)N * 64 + 255) / 256); // agg: 1 wave/node

    k_gemm<128, true ><<<gG, 256, 0, stream>>>(x,    wt1, dinv, g8, N);
    k_agg128<<<gA, 256, 0, stream>>>(g8, offs, endsA, csr, dinv, b1, hbuf, N);
    k_gemm<128, false><<<gG, 256, 0, stream>>>(hbuf, wt2, dinv, g8, N);
    k_agg128<<<gA, 256, 0, stream>>>(g8, offs, endsA, csr, dinv, b2, hbuf, N);
    k_gemm<64,  false><<<gG, 256, 0, stream>>>(hbuf, wt3, dinv, g8, N);
    k_agg64<<<gA, 256, 0, stream>>>(g8, offs, endsA, csr, dinv, b3, outp, N);
}

// Round 8
// 290.776 us; speedup vs baseline: 1.1249x; 1.1249x over previous
//
#include <hip/hip_runtime.h>

typedef unsigned int u32;
typedef unsigned short u16;
typedef unsigned char u8;
typedef long i64;
typedef __attribute__((ext_vector_type(8))) short short8;
typedef __attribute__((ext_vector_type(4))) float f32x4;

#define MAXBIN 1024   // bins of 128 dsts; N=100k -> 782 bins
#define SORT_TPB 1024 // threads/block for scatter: 16 waves/block for latency hiding
#define BINCAP 4096   // fixed binned capacity/bin: mean 2046, sigma~45 -> 45-sigma headroom
#define CSRCAP 5120   // fixed padded-csr capacity/bin: max padded = bincnt + 128*8 <= ~3300

__device__ inline u16 f2bf(float f) {
    u32 u = __builtin_bit_cast(u32, f);
    u32 r = (u + 0x7fffu + ((u >> 16) & 1u)) >> 16;  // RTNE
    return (u16)r;
}

// MFMA-as-summation: C[m][n] = sum_k A[m][k] * B[k][n], B[k][n] = 1.0 iff n == (k&7).
// A fragment = gathered fp8 rows (lane&15 = A-row m, lane>>4 = k-group/edge slot,
// 8 consecutive bytes per lane). C[m][n] += sum over slots of byte n of row m.
__device__ inline f32x4 mfma_fp8(uint2 a, uint2 b, f32x4 c) {
    return __builtin_amdgcn_mfma_f32_16x16x32_fp8_fp8(
        __builtin_bit_cast(i64, a), __builtin_bit_cast(i64, b), c, 0, 0, 0);
}

// Output-feature permutation induced by the MFMA C layout. Position p in the stored
// row holds true feature pi(p); pi is baked into wt2/wt3 k-dim (exact, free).
__device__ inline int permP(int p) {
    return ((p >> 5) << 5) + ((p & 3) << 3) + ((p >> 2) & 7);
}

// ---------- CSR build ----------
// R1: direct random 4B scatter = 106MB WRITE_SIZE (16x line amplification) -> binned.
// R2: 1024 threads/block fixed the occupancy latency bound.
// R8: fixed-capacity bins (BINCAP) kill k_bhist + k_bscan entirely: bscatter
// allocates per-block runs with one global atomicAdd per bin per block against
// fixed base bin*BINCAP. One edge-histogram pass instead of two.
// R7 lesson (counters): ILP batching in agg raised VGPR 24->40, occupancy 66->51%,
// +28% time -> REVERTED to R6 loop form. Wave supply is the latency hider.
__global__ __launch_bounds__(SORT_TPB) void k_bscatter(const int* __restrict__ ei, int E, int W,
                                                       int* __restrict__ binCnt,
                                                       u32* __restrict__ binned, int NBIN) {
    __shared__ int lh[MAXBIN];
    __shared__ int lb[MAXBIN];
    int tid = threadIdx.x;
    for (int i = tid; i < NBIN; i += SORT_TPB) lh[i] = 0;
    __syncthreads();
    int s = blockIdx.x * W, e = min(E, s + W);
    for (int j = s + tid; j < e; j += SORT_TPB) atomicAdd(&lh[ei[E + j] >> 7], 1);
    __syncthreads();
    for (int i = tid; i < NBIN; i += SORT_TPB) {
        int h = lh[i];
        int base = 0;
        if (h) {
            base = atomicAdd(&binCnt[i], h);
            if (base + h > BINCAP) base = BINCAP - h;  // fault-safety clamp (never expected)
        }
        lb[i] = i * BINCAP + base;
    }
    __syncthreads();
    for (int i = tid; i < NBIN; i += SORT_TPB) lh[i] = 0;
    __syncthreads();
    for (int j = s + tid; j < e; j += SORT_TPB) {
        int d = ei[E + j];
        int b = d >> 7;
        int r = atomicAdd(&lh[b], 1);
        binned[lb[b] + r] = ((u32)ei[j] << 7) | (u32)(d & 127);
    }
}

// Padded CSR at fixed per-bin base b*CSRCAP: per-dst slots pc = (c+1 self) rounded
// up to 8. Region sentinel-filled (N) over the used length, then self + real edges
// overwrite. offs[d] = start, ends[d] = start + pc (exact mult-8 range).
__global__ __launch_bounds__(256) void k_bcsr(const u32* __restrict__ binned,
                                              const int* __restrict__ binCnt,
                                              int N, int* __restrict__ offs,
                                              int* __restrict__ ends,
                                              float* __restrict__ dinv,
                                              int* __restrict__ csr) {
    __shared__ int cnt[128];
    __shared__ int off[128];
    __shared__ int tot;
    __shared__ int fillEnd;
    int b = blockIdx.x;
    int tid = threadIdx.x;
    int dLo = b << 7;
    int nd = min(128, N - dLo);
    int bbase = b * BINCAP;
    int gCnt = min(binCnt[b], BINCAP);
    int pbase = b * CSRCAP;
    if (tid < 128) cnt[tid] = 0;
    __syncthreads();
    for (int j = tid; j < gCnt; j += 256) atomicAdd(&cnt[binned[bbase + j] & 127u], 1);
    __syncthreads();
    int c = (tid < 128) ? cnt[tid] : 0;
    int pc = (tid < 128) ? ((c + 8) & ~7) : 0;  // (c+1 self) rounded up to 8
    int lane = tid & 63;
    int isc = pc;
    for (int d = 1; d < 64; d <<= 1) { int o = __shfl_up(isc, d, 64); if (lane >= d) isc += o; }
    if (tid == 63) tot = isc;
    __syncthreads();
    int add = (tid >= 64 && tid < 128) ? tot : 0;
    if (tid < 128) off[tid] = add + isc - pc;
    if (tid == 127) fillEnd = add + isc;  // total padded length for this bin
    __syncthreads();
    // sentinel-fill used padded region only
    for (int j = tid; j < fillEnd; j += 256) csr[pbase + j] = N;
    __syncthreads();
    if (tid < nd) {
        offs[dLo + tid] = pbase + off[tid];
        ends[dLo + tid] = pbase + off[tid] + pc;
        dinv[dLo + tid] = rsqrtf((float)(c + 1));
        csr[pbase + off[tid] + c] = dLo + tid;  // self-loop entry
    }
    if (tid < 128) cnt[tid] = 0;
    __syncthreads();
    for (int j = tid; j < gCnt; j += 256) {
        u32 v = binned[bbase + j];
        int d7 = (int)(v & 127u);
        int r = atomicAdd(&cnt[d7], 1);
        csr[pbase + off[d7] + r] = (int)(v >> 7);
    }
}

// ---------- fused weight converts (W[K][M] row-major -> Wt[M][K] bf16) ----------
// wt2/wt3 k-dim permuted by pi (agg128 stores feature pi(p) at position p).
__global__ void k_wtall(const float* __restrict__ W1, const float* __restrict__ W2,
                        const float* __restrict__ W3, u16* __restrict__ wt1,
                        u16* __restrict__ wt2, u16* __restrict__ wt3) {
    int idx = blockIdx.x * 256 + threadIdx.x;
    if (idx < 16384) {
        int k = idx >> 7, m = idx & 127;
        wt1[m * 128 + k] = f2bf(W1[idx]);
    } else if (idx < 32768) {
        int i = idx - 16384, p = i >> 7, m = i & 127;
        wt2[m * 128 + p] = f2bf(W2[permP(p) * 128 + m]);
    } else if (idx < 40960) {
        int i = idx - 32768, p = i >> 6, m = i & 63;
        wt3[m * 128 + p] = f2bf(W3[permP(p) * 64 + m]);
    }
}

// ---------- GEMM: g8 = fp8((x @ W) * dinv[row] * 16); also zeroes sentinel row N --
template <int M, bool F32IN>
__global__ __launch_bounds__(256) void k_gemm(const void* __restrict__ xin,
                                              const u16* __restrict__ wt,
                                              const float* __restrict__ dinv,
                                              u8* __restrict__ g8, int N) {
    constexpr int K = 128;
    constexpr int LDK = 136;
    __shared__ u16 lwt[M * LDK];
    int tid = threadIdx.x;
    if (blockIdx.x == 0 && tid < M / 16)  // keep sentinel row zero for padded agg
        *(uint4*)(g8 + (size_t)N * M + (size_t)tid * 16) = make_uint4(0u, 0u, 0u, 0u);
    const uint4* wsrc = (const uint4*)wt;
#pragma unroll
    for (int c = tid; c < M * K / 8; c += 256) {
        int row = c >> 4, kc = c & 15;
        *(uint4*)&lwt[row * LDK + kc * 8] = wsrc[c];
    }
    __syncthreads();
    int lane = tid & 63, wv = tid >> 6;
    int node = blockIdx.x * 64 + wv * 16 + (lane & 15);
    int nodec = min(node, N - 1);
    int kr = (lane >> 4) * 8;
    f32x4 acc[M / 16];
#pragma unroll
    for (int t = 0; t < M / 16; t++) acc[t] = (f32x4){0.f, 0.f, 0.f, 0.f};
#pragma unroll
    for (int ks = 0; ks < 4; ks++) {
        short8 bfr;
        if (F32IN) {
            const float* xr = (const float*)xin + (size_t)nodec * K + ks * 32 + kr;
            float4 fa = *(const float4*)xr;
            float4 fb = *(const float4*)(xr + 4);
            bfr = (short8){(short)f2bf(fa.x), (short)f2bf(fa.y), (short)f2bf(fa.z),
                           (short)f2bf(fa.w), (short)f2bf(fb.x), (short)f2bf(fb.y),
                           (short)f2bf(fb.z), (short)f2bf(fb.w)};
        } else {
            bfr = *(const short8*)((const u16*)xin + (size_t)nodec * K + ks * 32 + kr);
        }
#pragma unroll
        for (int t = 0; t < M / 16; t++) {
            short8 afr = *(const short8*)&lwt[(t * 16 + (lane & 15)) * LDK + ks * 32 + kr];
            acc[t] = __builtin_amdgcn_mfma_f32_16x16x32_bf16(afr, bfr, acc[t], 0, 0, 0);
        }
    }
    if (node < N) {
        float dv16 = dinv[node] * 16.0f;
        int r0 = (lane >> 4) * 4;
#pragma unroll
        for (int t = 0; t < M / 16; t++) {
            u32 w = __builtin_amdgcn_cvt_pk_fp8_f32(acc[t][0] * dv16, acc[t][1] * dv16, 0, false);
            w = __builtin_amdgcn_cvt_pk_fp8_f32(acc[t][2] * dv16, acc[t][3] * dv16, w, true);
            *(u32*)(g8 + (size_t)node * M + t * 16 + r0) = w;
        }
    }
}

// ---------- aggregation via MFMA, mask-free on padded csr (R6 proven form) ----------
// pad mult-8; main loop step 16 (4 MFMA) + wave-uniform tail-8 (2 MFMA).
// No per-lane masks anywhere. VGPR 24, occupancy ~66% -- do NOT widen batches (R7).
__global__ __launch_bounds__(256) void k_agg128(const u8* __restrict__ g8,
                                                const int* __restrict__ offs,
                                                const int* __restrict__ ends,
                                                const int* __restrict__ csr,
                                                const float* __restrict__ dinv,
                                                const float* __restrict__ bias,
                                                u16* __restrict__ hout, int N) {
    int wid = (blockIdx.x * 256 + threadIdx.x) >> 6;  // one wave per node
    if (wid >= N) return;
    int lane = threadIdx.x & 63;
    int q = lane >> 4;   // edge slot within each MFMA
    int f = lane & 15;   // A-row: feature chunk (bytes f*8..f*8+7 of each row)
    int s = offs[wid], e = ends[wid];
    uint2 bsel;
    bsel.x = (f < 4) ? (0x38u << (8 * f)) : 0u;               // fp8 e4m3 1.0 = 0x38
    bsel.y = (f >= 4 && f < 8) ? (0x38u << (8 * (f - 4))) : 0u;
    const u8* gf = g8 + f * 8;
    f32x4 ac0 = {0.f, 0.f, 0.f, 0.f}, ac1 = ac0, ac2 = ac0, ac3 = ac0;
    int j = s;
    for (; j + 16 <= e; j += 16) {
        int s0 = csr[j + q];
        int s1 = csr[j + 4 + q];
        int s2 = csr[j + 8 + q];
        int s3 = csr[j + 12 + q];
        uint2 w0 = *(const uint2*)(gf + ((u32)s0 << 7));
        uint2 w1 = *(const uint2*)(gf + ((u32)s1 << 7));
        uint2 w2 = *(const uint2*)(gf + ((u32)s2 << 7));
        uint2 w3 = *(const uint2*)(gf + ((u32)s3 << 7));
        ac0 = mfma_fp8(w0, bsel, ac0);
        ac1 = mfma_fp8(w1, bsel, ac1);
        ac2 = mfma_fp8(w2, bsel, ac2);
        ac3 = mfma_fp8(w3, bsel, ac3);
    }
    if (j < e) {  // wave-uniform tail: exactly 8 slots
        int s0 = csr[j + q];
        int s1 = csr[j + 4 + q];
        uint2 w0 = *(const uint2*)(gf + ((u32)s0 << 7));
        uint2 w1 = *(const uint2*)(gf + ((u32)s1 << 7));
        ac0 = mfma_fp8(w0, bsel, ac0);
        ac1 = mfma_fp8(w1, bsel, ac1);
    }
    f32x4 a = (ac0 + ac1) + (ac2 + ac3);
    // C layout: col = lane&15 (= n, valid <8), row = (lane>>4)*4 + r (= feature chunk)
    int jn = lane & 15, fq = lane >> 4;
    if (jn < 8) {
        float sc = dinv[wid] * 0.0625f;
        u32 o0, o1;
        {
            float v0 = fmaxf(fmaf(a[0], sc, bias[(4 * fq + 0) * 8 + jn]), 0.f);
            float v1 = fmaxf(fmaf(a[1], sc, bias[(4 * fq + 1) * 8 + jn]), 0.f);
            o0 = (u32)f2bf(v0) | ((u32)f2bf(v1) << 16);
        }
        {
            float v2 = fmaxf(fmaf(a[2], sc, bias[(4 * fq + 2) * 8 + jn]), 0.f);
            float v3 = fmaxf(fmaf(a[3], sc, bias[(4 * fq + 3) * 8 + jn]), 0.f);
            o1 = (u32)f2bf(v2) | ((u32)f2bf(v3) << 16);
        }
        // permuted store: position p = fq*32 + jn*4 + r holds feature (4fq+r)*8+jn
        *(uint2*)&hout[(size_t)wid * 128 + fq * 32 + jn * 4] = make_uint2(o0, o1);
    }
}

// ---------- layer-3 aggregation + log_softmax (F=64), full-lane MFMA (R6 form) ----
// A-rows 8-15 carry a SECOND edge half-set of the same node: 8 edges/MFMA.
// Main loop step 16 (2 MFMA) + wave-uniform tail-8 (1 MFMA); shfl_xor(32) combine.
__global__ __launch_bounds__(256) void k_agg64(const u8* __restrict__ g8,
                                               const int* __restrict__ offs,
                                               const int* __restrict__ ends,
                                               const int* __restrict__ csr,
                                               const float* __restrict__ dinv,
                                               const float* __restrict__ bias,
                                               float* __restrict__ out, int N) {
    __shared__ float sm[4][64];
    int wid = (blockIdx.x * 256 + threadIdx.x) >> 6;
    if (wid >= N) return;
    int lane = threadIdx.x & 63;
    int wv = (int)(threadIdx.x >> 6);
    int q = lane >> 4;
    int f = lane & 15;
    int qq = q + ((f >> 3) << 2);  // edge slot 0..7 within window half
    int s = offs[wid], e = ends[wid];
    uint2 bsel;
    bsel.x = (f < 4) ? (0x38u << (8 * f)) : 0u;
    bsel.y = (f >= 4 && f < 8) ? (0x38u << (8 * (f - 4))) : 0u;
    const u8* gf = g8 + (f & 7) * 8;
    f32x4 ac0 = {0.f, 0.f, 0.f, 0.f}, ac1 = ac0;
    int j = s;
    for (; j + 16 <= e; j += 16) {
        int sA = csr[j + qq];
        int sB = csr[j + 8 + qq];
        uint2 wA = *(const uint2*)(gf + ((u32)sA << 6));
        uint2 wB = *(const uint2*)(gf + ((u32)sB << 6));
        ac0 = mfma_fp8(wA, bsel, ac0);
        ac1 = mfma_fp8(wB, bsel, ac1);
    }
    if (j < e) {  // wave-uniform tail: exactly 8 slots
        int sA = csr[j + qq];
        uint2 wA = *(const uint2*)(gf + ((u32)sA << 6));
        ac0 = mfma_fp8(wA, bsel, ac0);
    }
    f32x4 a = ac0 + ac1;
#pragma unroll
    for (int r = 0; r < 4; r++) a[r] += __shfl_xor(a[r], 32, 64);
    int jn = lane & 15, fq = lane >> 4;
    bool act = (jn < 8) && (fq < 2);  // lanes 0-31 hold combined chunks 0-7
    if (act) {
        float sc = dinv[wid] * 0.0625f;
        float v0 = fmaf(a[0], sc, bias[(4 * fq + 0) * 8 + jn]);
        float v1 = fmaf(a[1], sc, bias[(4 * fq + 1) * 8 + jn]);
        float v2 = fmaf(a[2], sc, bias[(4 * fq + 2) * 8 + jn]);
        float v3 = fmaf(a[3], sc, bias[(4 * fq + 3) * 8 + jn]);
        float m = fmaxf(fmaxf(v0, v1), fmaxf(v2, v3));
        m = fmaxf(m, __shfl_xor(m, 1, 64));
        m = fmaxf(m, __shfl_xor(m, 2, 64));
        m = fmaxf(m, __shfl_xor(m, 4, 64));
        m = fmaxf(m, __shfl_xor(m, 16, 64));
        float ss = __expf(v0 - m) + __expf(v1 - m) + __expf(v2 - m) + __expf(v3 - m);
        ss += __shfl_xor(ss, 1, 64);
        ss += __shfl_xor(ss, 2, 64);
        ss += __shfl_xor(ss, 4, 64);
        ss += __shfl_xor(ss, 16, 64);
        float lg = m + __logf(ss);
        sm[wv][(4 * fq + 0) * 8 + jn] = v0 - lg;
        sm[wv][(4 * fq + 1) * 8 + jn] = v1 - lg;
        sm[wv][(4 * fq + 2) * 8 + jn] = v2 - lg;
        sm[wv][(4 * fq + 3) * 8 + jn] = v3 - lg;
    }
    // same-wave LDS bounce to standard order (compiler inserts lgkmcnt wait)
    if (lane < 16) {
        float4 ov = *(float4*)&sm[wv][lane * 4];
        *(float4*)&out[(size_t)wid * 64 + lane * 4] = ov;
    }
}

extern "C" void kernel_launch(void* const* d_in, const int* in_sizes, int n_in,
                              void* d_out, int out_size, void* d_ws, size_t ws_size,
                              hipStream_t stream) {
    const float* x  = (const float*)d_in[0];
    const int*   ei = (const int*)d_in[1];
    const float* W1 = (const float*)d_in[2];
    const float* b1 = (const float*)d_in[3];
    const float* W2 = (const float*)d_in[4];
    const float* b2 = (const float*)d_in[5];
    const float* W3 = (const float*)d_in[6];
    const float* b3 = (const float*)d_in[7];
    const int N = in_sizes[0] / 128;
    const int E = in_sizes[1] / 2;
    const int NBIN = (N + 127) >> 7;  // bins of 128 dsts

    char* ws = (char*)d_ws;
    size_t o = 0;
    auto alloc = [&](size_t bytes) -> char* {
        char* p = ws + o;
        o += (bytes + 255) & ~(size_t)255;
        return p;
    };
    int*   binCnt = (int*)alloc((size_t)MAXBIN * 4);
    float* dinv   = (float*)alloc((size_t)N * 4);
    int*   offs   = (int*)alloc((size_t)N * 4);
    int*   endsA  = (int*)alloc((size_t)N * 4);
    int*   csr    = (int*)alloc((size_t)NBIN * CSRCAP * 4);
    u16*   wt1    = (u16*)alloc(128 * 128 * 2);
    u16*   wt2    = (u16*)alloc(128 * 128 * 2);
    u16*   wt3    = (u16*)alloc(64 * 128 * 2);
    u8*    g8     = (u8*)alloc(((size_t)N + 1) * 128);  // +1: zero sentinel row
    u16*   hbuf   = (u16*)alloc((size_t)N * 128 * 2);
    u32*   binned = (u32*)hbuf;  // alias (16MB <= 25.6MB): dead before first agg write
    float* outp   = (float*)d_out;

    hipMemsetAsync(binCnt, 0, (size_t)MAXBIN * 4, stream);
    int W256 = (E + 255) / 256;  // edges per block at 256 blocks
    k_bscatter<<<256, SORT_TPB, 0, stream>>>(ei, E, W256, binCnt, binned, NBIN);
    k_bcsr<<<NBIN, 256, 0, stream>>>(binned, binCnt, N, offs, endsA, dinv, csr);
    k_wtall<<<(40960 + 255) / 256, 256, 0, stream>>>(W1, W2, W3, wt1, wt2, wt3);

    int gG = (N + 63) / 64;                       // GEMM: 64 nodes/block
    int gA = (int)(((size_t)N * 64 + 255) / 256); // agg: 1 wave/node

    k_gemm<128, true ><<<gG, 256, 0, stream>>>(x,    wt1, dinv, g8, N);
    k_agg128<<<gA, 256, 0, stream>>>(g8, offs, endsA, csr, dinv, b1, hbuf, N);
    k_gemm<128, false><<<gG, 256, 0, stream>>>(hbuf, wt2, dinv, g8, N);
    k_agg128<<<gA, 256, 0, stream>>>(g8, offs, endsA, csr, dinv, b2, hbuf, N);
    k_gemm<64,  false><<<gG, 256, 0, stream>>>(hbuf, wt3, dinv, g8, N);
    k_agg64<<<gA, 256, 0, stream>>>(g8, offs, endsA, csr, dinv, b3, outp, N);
}

// Round 9
// 288.759 us; speedup vs baseline: 1.1328x; 1.0070x over previous
//
#include <hip/hip_runtime.h>

typedef unsigned int u32;
typedef unsigned short u16;
typedef unsigned char u8;
typedef long i64;
typedef __attribute__((ext_vector_type(8))) short short8;
typedef __attribute__((ext_vector_type(4))) float f32x4;

#define MAXBIN 1024   // bins of 128 dsts; N=100k -> 782 bins
#define SORT_TPB 1024 // threads/block for scatter: 16 waves/block for latency hiding
#define BINCAP 4096   // fixed binned capacity/bin: mean 2046, sigma~45 -> 45-sigma headroom
#define CSRCAP 5120   // fixed padded-csr capacity/bin: max padded = bincnt + 128*8 <= ~3300

__device__ inline u16 f2bf(float f) {
    u32 u = __builtin_bit_cast(u32, f);
    u32 r = (u + 0x7fffu + ((u >> 16) & 1u)) >> 16;  // RTNE
    return (u16)r;
}

// MFMA-as-summation: C[m][n] = sum_k A[m][k] * B[k][n], B[k][n] = 1.0 iff n == (k&7).
// A fragment = gathered fp8 rows (lane&15 = A-row m, lane>>4 = k-group/edge slot,
// 8 consecutive bytes per lane). C[m][n] += sum over slots of byte n of row m.
__device__ inline f32x4 mfma_fp8(uint2 a, uint2 b, f32x4 c) {
    return __builtin_amdgcn_mfma_f32_16x16x32_fp8_fp8(
        __builtin_bit_cast(i64, a), __builtin_bit_cast(i64, b), c, 0, 0, 0);
}

// Output-feature permutation induced by the MFMA C layout. Position p in the stored
// row holds true feature pi(p); pi is baked into wt2/wt3 k-dim (exact, free).
__device__ inline int permP(int p) {
    return ((p >> 5) << 5) + ((p & 3) << 3) + ((p >> 2) & 7);
}

// ---------- CSR build ----------
// R1: direct random 4B scatter = 106MB WRITE_SIZE (16x line amplification) -> binned.
// R2: 1024 threads/block fixed the occupancy latency bound.
// R8: fixed-capacity bins (BINCAP) killed k_bhist + k_bscan (-13us): bscatter
// allocates per-block runs with one global atomicAdd per bin per block.
__global__ __launch_bounds__(SORT_TPB) void k_bscatter(const int* __restrict__ ei, int E, int W,
                                                       int* __restrict__ binCnt,
                                                       u32* __restrict__ binned, int NBIN) {
    __shared__ int lh[MAXBIN];
    __shared__ int lb[MAXBIN];
    int tid = threadIdx.x;
    for (int i = tid; i < NBIN; i += SORT_TPB) lh[i] = 0;
    __syncthreads();
    int s = blockIdx.x * W, e = min(E, s + W);
    for (int j = s + tid; j < e; j += SORT_TPB) atomicAdd(&lh[ei[E + j] >> 7], 1);
    __syncthreads();
    for (int i = tid; i < NBIN; i += SORT_TPB) {
        int h = lh[i];
        int base = 0;
        if (h) {
            base = atomicAdd(&binCnt[i], h);
            if (base + h > BINCAP) base = BINCAP - h;  // fault-safety clamp (never expected)
        }
        lb[i] = i * BINCAP + base;
    }
    __syncthreads();
    for (int i = tid; i < NBIN; i += SORT_TPB) lh[i] = 0;
    __syncthreads();
    for (int j = s + tid; j < e; j += SORT_TPB) {
        int d = ei[E + j];
        int b = d >> 7;
        int r = atomicAdd(&lh[b], 1);
        binned[lb[b] + r] = ((u32)ei[j] << 7) | (u32)(d & 127);
    }
}

// Padded CSR at fixed per-bin base b*CSRCAP: per-dst slots pc = (c+1 self) rounded
// up to 8. Region sentinel-filled (N) over the used length, then self + real edges
// overwrite. offs[d] = start, ends[d] = start + pc (exact mult-8 range).
__global__ __launch_bounds__(256) void k_bcsr(const u32* __restrict__ binned,
                                              const int* __restrict__ binCnt,
                                              int N, int* __restrict__ offs,
                                              int* __restrict__ ends,
                                              float* __restrict__ dinv,
                                              int* __restrict__ csr) {
    __shared__ int cnt[128];
    __shared__ int off[128];
    __shared__ int tot;
    __shared__ int fillEnd;
    int b = blockIdx.x;
    int tid = threadIdx.x;
    int dLo = b << 7;
    int nd = min(128, N - dLo);
    int bbase = b * BINCAP;
    int gCnt = min(binCnt[b], BINCAP);
    int pbase = b * CSRCAP;
    if (tid < 128) cnt[tid] = 0;
    __syncthreads();
    for (int j = tid; j < gCnt; j += 256) atomicAdd(&cnt[binned[bbase + j] & 127u], 1);
    __syncthreads();
    int c = (tid < 128) ? cnt[tid] : 0;
    int pc = (tid < 128) ? ((c + 8) & ~7) : 0;  // (c+1 self) rounded up to 8
    int lane = tid & 63;
    int isc = pc;
    for (int d = 1; d < 64; d <<= 1) { int o = __shfl_up(isc, d, 64); if (lane >= d) isc += o; }
    if (tid == 63) tot = isc;
    __syncthreads();
    int add = (tid >= 64 && tid < 128) ? tot : 0;
    if (tid < 128) off[tid] = add + isc - pc;
    if (tid == 127) fillEnd = add + isc;  // total padded length for this bin
    __syncthreads();
    // sentinel-fill used padded region only
    for (int j = tid; j < fillEnd; j += 256) csr[pbase + j] = N;
    __syncthreads();
    if (tid < nd) {
        offs[dLo + tid] = pbase + off[tid];
        ends[dLo + tid] = pbase + off[tid] + pc;
        dinv[dLo + tid] = rsqrtf((float)(c + 1));
        csr[pbase + off[tid] + c] = dLo + tid;  // self-loop entry
    }
    if (tid < 128) cnt[tid] = 0;
    __syncthreads();
    for (int j = tid; j < gCnt; j += 256) {
        u32 v = binned[bbase + j];
        int d7 = (int)(v & 127u);
        int r = atomicAdd(&cnt[d7], 1);
        csr[pbase + off[d7] + r] = (int)(v >> 7);
    }
}

// ---------- fused weight converts (W[K][M] row-major -> Wt[M][K] bf16) ----------
// wt2/wt3 k-dim permuted by pi (agg128 stores feature pi(p) at position p).
__global__ void k_wtall(const float* __restrict__ W1, const float* __restrict__ W2,
                        const float* __restrict__ W3, u16* __restrict__ wt1,
                        u16* __restrict__ wt2, u16* __restrict__ wt3) {
    int idx = blockIdx.x * 256 + threadIdx.x;
    if (idx < 16384) {
        int k = idx >> 7, m = idx & 127;
        wt1[m * 128 + k] = f2bf(W1[idx]);
    } else if (idx < 32768) {
        int i = idx - 16384, p = i >> 7, m = i & 127;
        wt2[m * 128 + p] = f2bf(W2[permP(p) * 128 + m]);
    } else if (idx < 40960) {
        int i = idx - 32768, p = i >> 6, m = i & 63;
        wt3[m * 128 + p] = f2bf(W3[permP(p) * 64 + m]);
    }
}

// ---------- GEMM: g8 = fp8((x @ W) * dinv[row] * 16); also zeroes sentinel row N --
template <int M, bool F32IN>
__global__ __launch_bounds__(256) void k_gemm(const void* __restrict__ xin,
                                              const u16* __restrict__ wt,
                                              const float* __restrict__ dinv,
                                              u8* __restrict__ g8, int N) {
    constexpr int K = 128;
    constexpr int LDK = 136;
    __shared__ u16 lwt[M * LDK];
    int tid = threadIdx.x;
    if (blockIdx.x == 0 && tid < M / 16)  // keep sentinel row zero for padded agg
        *(uint4*)(g8 + (size_t)N * M + (size_t)tid * 16) = make_uint4(0u, 0u, 0u, 0u);
    const uint4* wsrc = (const uint4*)wt;
#pragma unroll
    for (int c = tid; c < M * K / 8; c += 256) {
        int row = c >> 4, kc = c & 15;
        *(uint4*)&lwt[row * LDK + kc * 8] = wsrc[c];
    }
    __syncthreads();
    int lane = tid & 63, wv = tid >> 6;
    int node = blockIdx.x * 64 + wv * 16 + (lane & 15);
    int nodec = min(node, N - 1);
    int kr = (lane >> 4) * 8;
    f32x4 acc[M / 16];
#pragma unroll
    for (int t = 0; t < M / 16; t++) acc[t] = (f32x4){0.f, 0.f, 0.f, 0.f};
#pragma unroll
    for (int ks = 0; ks < 4; ks++) {
        short8 bfr;
        if (F32IN) {
            const float* xr = (const float*)xin + (size_t)nodec * K + ks * 32 + kr;
            float4 fa = *(const float4*)xr;
            float4 fb = *(const float4*)(xr + 4);
            bfr = (short8){(short)f2bf(fa.x), (short)f2bf(fa.y), (short)f2bf(fa.z),
                           (short)f2bf(fa.w), (short)f2bf(fb.x), (short)f2bf(fb.y),
                           (short)f2bf(fb.z), (short)f2bf(fb.w)};
        } else {
            bfr = *(const short8*)((const u16*)xin + (size_t)nodec * K + ks * 32 + kr);
        }
#pragma unroll
        for (int t = 0; t < M / 16; t++) {
            short8 afr = *(const short8*)&lwt[(t * 16 + (lane & 15)) * LDK + ks * 32 + kr];
            acc[t] = __builtin_amdgcn_mfma_f32_16x16x32_bf16(afr, bfr, acc[t], 0, 0, 0);
        }
    }
    if (node < N) {
        float dv16 = dinv[node] * 16.0f;
        int r0 = (lane >> 4) * 4;
#pragma unroll
        for (int t = 0; t < M / 16; t++) {
            u32 w = __builtin_amdgcn_cvt_pk_fp8_f32(acc[t][0] * dv16, acc[t][1] * dv16, 0, false);
            w = __builtin_amdgcn_cvt_pk_fp8_f32(acc[t][2] * dv16, acc[t][3] * dv16, w, true);
            *(u32*)(g8 + (size_t)node * M + t * 16 + r0) = w;
        }
    }
}

// ---------- aggregation via MFMA, mask-free, csr-index software pipeline ----------
// R8 counters: agg64 (half the bytes/loads of agg128) takes the SAME 40us ->
// bound by the per-wave serial chain csr->gather->mfma, not bytes or issue.
// R9: rotate the csr index loads one window ahead (indices only, +~4 VGPR --
// NOT the R7 mistake of batching gathers, which cost 16 VGPRs and occupancy).
// Chain shrinks from (csr + gather) to ~gather per trip. Over-reads stay inside
// the bin's fixed-capacity slack (+64-int margin on the allocation).
__global__ __launch_bounds__(256) void k_agg128(const u8* __restrict__ g8,
                                                const int* __restrict__ offs,
                                                const int* __restrict__ ends,
                                                const int* __restrict__ csr,
                                                const float* __restrict__ dinv,
                                                const float* __restrict__ bias,
                                                u16* __restrict__ hout, int N) {
    int wid = (blockIdx.x * 256 + threadIdx.x) >> 6;  // one wave per node
    if (wid >= N) return;
    int lane = threadIdx.x & 63;
    int q = lane >> 4;   // edge slot within each MFMA
    int f = lane & 15;   // A-row: feature chunk (bytes f*8..f*8+7 of each row)
    int s = offs[wid], e = ends[wid];
    uint2 bsel;
    bsel.x = (f < 4) ? (0x38u << (8 * f)) : 0u;               // fp8 e4m3 1.0 = 0x38
    bsel.y = (f >= 4 && f < 8) ? (0x38u << (8 * (f - 4))) : 0u;
    const u8* gf = g8 + f * 8;
    f32x4 ac0 = {0.f, 0.f, 0.f, 0.f}, ac1 = ac0, ac2 = ac0, ac3 = ac0;
    int j = s;
    // preload window-0 indices (i2/i3 may over-read into bin slack: safe, unused)
    int i0 = csr[j + q];
    int i1 = csr[j + 4 + q];
    int i2 = csr[j + 8 + q];
    int i3 = csr[j + 12 + q];
    for (; j + 16 <= e; j += 16) {
        uint2 w0 = *(const uint2*)(gf + ((u32)i0 << 7));
        uint2 w1 = *(const uint2*)(gf + ((u32)i1 << 7));
        uint2 w2 = *(const uint2*)(gf + ((u32)i2 << 7));
        uint2 w3 = *(const uint2*)(gf + ((u32)i3 << 7));
        i0 = csr[j + 16 + q];   // prefetch next window under this window's gathers
        i1 = csr[j + 20 + q];
        i2 = csr[j + 24 + q];
        i3 = csr[j + 28 + q];
        ac0 = mfma_fp8(w0, bsel, ac0);
        ac1 = mfma_fp8(w1, bsel, ac1);
        ac2 = mfma_fp8(w2, bsel, ac2);
        ac3 = mfma_fp8(w3, bsel, ac3);
    }
    if (j < e) {  // wave-uniform tail: exactly 8 slots, indices already in i0/i1
        uint2 w0 = *(const uint2*)(gf + ((u32)i0 << 7));
        uint2 w1 = *(const uint2*)(gf + ((u32)i1 << 7));
        ac0 = mfma_fp8(w0, bsel, ac0);
        ac1 = mfma_fp8(w1, bsel, ac1);
    }
    f32x4 a = (ac0 + ac1) + (ac2 + ac3);
    // C layout: col = lane&15 (= n, valid <8), row = (lane>>4)*4 + r (= feature chunk)
    int jn = lane & 15, fq = lane >> 4;
    if (jn < 8) {
        float sc = dinv[wid] * 0.0625f;
        u32 o0, o1;
        {
            float v0 = fmaxf(fmaf(a[0], sc, bias[(4 * fq + 0) * 8 + jn]), 0.f);
            float v1 = fmaxf(fmaf(a[1], sc, bias[(4 * fq + 1) * 8 + jn]), 0.f);
            o0 = (u32)f2bf(v0) | ((u32)f2bf(v1) << 16);
        }
        {
            float v2 = fmaxf(fmaf(a[2], sc, bias[(4 * fq + 2) * 8 + jn]), 0.f);
            float v3 = fmaxf(fmaf(a[3], sc, bias[(4 * fq + 3) * 8 + jn]), 0.f);
            o1 = (u32)f2bf(v2) | ((u32)f2bf(v3) << 16);
        }
        // permuted store: position p = fq*32 + jn*4 + r holds feature (4fq+r)*8+jn
        *(uint2*)&hout[(size_t)wid * 128 + fq * 32 + jn * 4] = make_uint2(o0, o1);
    }
}

// ---------- layer-3 aggregation + log_softmax (F=64), full-lane MFMA ----------
// A-rows 8-15 carry a SECOND edge half-set of the same node: 8 edges/MFMA.
// Same csr-index pipeline; shfl_xor(32) combines the halves.
__global__ __launch_bounds__(256) void k_agg64(const u8* __restrict__ g8,
                                               const int* __restrict__ offs,
                                               const int* __restrict__ ends,
                                               const int* __restrict__ csr,
                                               const float* __restrict__ dinv,
                                               const float* __restrict__ bias,
                                               float* __restrict__ out, int N) {
    __shared__ float sm[4][64];
    int wid = (blockIdx.x * 256 + threadIdx.x) >> 6;
    if (wid >= N) return;
    int lane = threadIdx.x & 63;
    int wv = (int)(threadIdx.x >> 6);
    int q = lane >> 4;
    int f = lane & 15;
    int qq = q + ((f >> 3) << 2);  // edge slot 0..7 within window half
    int s = offs[wid], e = ends[wid];
    uint2 bsel;
    bsel.x = (f < 4) ? (0x38u << (8 * f)) : 0u;
    bsel.y = (f >= 4 && f < 8) ? (0x38u << (8 * (f - 4))) : 0u;
    const u8* gf = g8 + (f & 7) * 8;
    f32x4 ac0 = {0.f, 0.f, 0.f, 0.f}, ac1 = ac0;
    int j = s;
    int iA = csr[j + qq];      // preload (iB may over-read into slack: safe)
    int iB = csr[j + 8 + qq];
    for (; j + 16 <= e; j += 16) {
        uint2 wA = *(const uint2*)(gf + ((u32)iA << 6));
        uint2 wB = *(const uint2*)(gf + ((u32)iB << 6));
        iA = csr[j + 16 + qq];  // prefetch next window
        iB = csr[j + 24 + qq];
        ac0 = mfma_fp8(wA, bsel, ac0);
        ac1 = mfma_fp8(wB, bsel, ac1);
    }
    if (j < e) {  // wave-uniform tail: exactly 8 slots
        uint2 wA = *(const uint2*)(gf + ((u32)iA << 6));
        ac0 = mfma_fp8(wA, bsel, ac0);
    }
    f32x4 a = ac0 + ac1;
#pragma unroll
    for (int r = 0; r < 4; r++) a[r] += __shfl_xor(a[r], 32, 64);
    int jn = lane & 15, fq = lane >> 4;
    bool act = (jn < 8) && (fq < 2);  // lanes 0-31 hold combined chunks 0-7
    if (act) {
        float sc = dinv[wid] * 0.0625f;
        float v0 = fmaf(a[0], sc, bias[(4 * fq + 0) * 8 + jn]);
        float v1 = fmaf(a[1], sc, bias[(4 * fq + 1) * 8 + jn]);
        float v2 = fmaf(a[2], sc, bias[(4 * fq + 2) * 8 + jn]);
        float v3 = fmaf(a[3], sc, bias[(4 * fq + 3) * 8 + jn]);
        float m = fmaxf(fmaxf(v0, v1), fmaxf(v2, v3));
        m = fmaxf(m, __shfl_xor(m, 1, 64));
        m = fmaxf(m, __shfl_xor(m, 2, 64));
        m = fmaxf(m, __shfl_xor(m, 4, 64));
        m = fmaxf(m, __shfl_xor(m, 16, 64));
        float ss = __expf(v0 - m) + __expf(v1 - m) + __expf(v2 - m) + __expf(v3 - m);
        ss += __shfl_xor(ss, 1, 64);
        ss += __shfl_xor(ss, 2, 64);
        ss += __shfl_xor(ss, 4, 64);
        ss += __shfl_xor(ss, 16, 64);
        float lg = m + __logf(ss);
        sm[wv][(4 * fq + 0) * 8 + jn] = v0 - lg;
        sm[wv][(4 * fq + 1) * 8 + jn] = v1 - lg;
        sm[wv][(4 * fq + 2) * 8 + jn] = v2 - lg;
        sm[wv][(4 * fq + 3) * 8 + jn] = v3 - lg;
    }
    // same-wave LDS bounce to standard order (compiler inserts lgkmcnt wait)
    if (lane < 16) {
        float4 ov = *(float4*)&sm[wv][lane * 4];
        *(float4*)&out[(size_t)wid * 64 + lane * 4] = ov;
    }
}

extern "C" void kernel_launch(void* const* d_in, const int* in_sizes, int n_in,
                              void* d_out, int out_size, void* d_ws, size_t ws_size,
                              hipStream_t stream) {
    const float* x  = (const float*)d_in[0];
    const int*   ei = (const int*)d_in[1];
    const float* W1 = (const float*)d_in[2];
    const float* b1 = (const float*)d_in[3];
    const float* W2 = (const float*)d_in[4];
    const float* b2 = (const float*)d_in[5];
    const float* W3 = (const float*)d_in[6];
    const float* b3 = (const float*)d_in[7];
    const int N = in_sizes[0] / 128;
    const int E = in_sizes[1] / 2;
    const int NBIN = (N + 127) >> 7;  // bins of 128 dsts

    char* ws = (char*)d_ws;
    size_t o = 0;
    auto alloc = [&](size_t bytes) -> char* {
        char* p = ws + o;
        o += (bytes + 255) & ~(size_t)255;
        return p;
    };
    int*   binCnt = (int*)alloc((size_t)MAXBIN * 4);
    float* dinv   = (float*)alloc((size_t)N * 4);
    int*   offs   = (int*)alloc((size_t)N * 4);
    int*   endsA  = (int*)alloc((size_t)N * 4);
    int*   csr    = (int*)alloc(((size_t)NBIN * CSRCAP + 64) * 4);  // +64: prefetch slack
    u16*   wt1    = (u16*)alloc(128 * 128 * 2);
    u16*   wt2    = (u16*)alloc(128 * 128 * 2);
    u16*   wt3    = (u16*)alloc(64 * 128 * 2);
    u8*    g8     = (u8*)alloc(((size_t)N + 1) * 128);  // +1: zero sentinel row
    u16*   hbuf   = (u16*)alloc((size_t)N * 128 * 2);
    u32*   binned = (u32*)hbuf;  // alias (16MB <= 25.6MB): dead before first agg write
    float* outp   = (float*)d_out;

    hipMemsetAsync(binCnt, 0, (size_t)MAXBIN * 4, stream);
    int W256 = (E + 255) / 256;  // edges per block at 256 blocks
    k_bscatter<<<256, SORT_TPB, 0, stream>>>(ei, E, W256, binCnt, binned, NBIN);
    k_bcsr<<<NBIN, 256, 0, stream>>>(binned, binCnt, N, offs, endsA, dinv, csr);
    k_wtall<<<(40960 + 255) / 256, 256, 0, stream>>>(W1, W2, W3, wt1, wt2, wt3);

    int gG = (N + 63) / 64;                       // GEMM: 64 nodes/block
    int gA = (int)(((size_t)N * 64 + 255) / 256); // agg: 1 wave/node

    k_gemm<128, true ><<<gG, 256, 0, stream>>>(x,    wt1, dinv, g8, N);
    k_agg128<<<gA, 256, 0, stream>>>(g8, offs, endsA, csr, dinv, b1, hbuf, N);
    k_gemm<128, false><<<gG, 256, 0, stream>>>(hbuf, wt2, dinv, g8, N);
    k_agg128<<<gA, 256, 0, stream>>>(g8, offs, endsA, csr, dinv, b2, hbuf, N);
    k_gemm<64,  false><<<gG, 256, 0, stream>>>(hbuf, wt3, dinv, g8, N);
    k_agg64<<<gA, 256, 0, stream>>>(g8, offs, endsA, csr, dinv, b3, outp, N);
}

// Round 10
// 277.789 us; speedup vs baseline: 1.1775x; 1.0395x over previous
//
#include <hip/hip_runtime.h>

typedef unsigned int u32;
typedef unsigned short u16;
typedef unsigned char u8;
typedef long i64;
typedef __attribute__((ext_vector_type(8))) short short8;
typedef __attribute__((ext_vector_type(4))) float f32x4;

#define MAXBIN 1024   // bins of 128 dsts; N=100k -> 782 bins
#define SORT_TPB 1024 // threads/block for scatter: 16 waves/block for latency hiding
#define BINCAP 4096   // fixed binned capacity/bin: mean 2046, sigma~45 -> 45-sigma headroom
#define CSRCAP 5120   // fixed padded-csr capacity/bin: max padded = bincnt + 128*8 <= ~3300

__device__ inline u16 f2bf(float f) {
    u32 u = __builtin_bit_cast(u32, f);
    u32 r = (u + 0x7fffu + ((u >> 16) & 1u)) >> 16;  // RTNE
    return (u16)r;
}

// MFMA-as-summation. A fragment = gathered fp8 rows (lane&15 = A-row m,
// lane>>4 = k-group/edge slot, 8 bytes per lane). B selector routes byte n of
// selected k-groups into column n. C[m][n] accumulates feature sums.
__device__ inline f32x4 mfma_fp8(uint2 a, uint2 b, f32x4 c) {
    return __builtin_amdgcn_mfma_f32_16x16x32_fp8_fp8(
        __builtin_bit_cast(i64, a), __builtin_bit_cast(i64, b), c, 0, 0, 0);
}

// Output-feature permutation induced by the MFMA C layout. Position p in the stored
// row holds true feature pi(p); pi is baked into wt2/wt3 k-dim (exact, free).
__device__ inline int permP(int p) {
    return ((p >> 5) << 5) + ((p & 3) << 3) + ((p >> 2) & 7);
}

// ---------- CSR build ----------
// R1: direct random 4B scatter = 106MB WRITE_SIZE (16x line amplification) -> binned.
// R2: 1024 threads/block fixed the occupancy latency bound.
// R8: fixed-capacity bins (BINCAP) killed k_bhist + k_bscan (-13us).
__global__ __launch_bounds__(SORT_TPB) void k_bscatter(const int* __restrict__ ei, int E, int W,
                                                       int* __restrict__ binCnt,
                                                       u32* __restrict__ binned, int NBIN) {
    __shared__ int lh[MAXBIN];
    __shared__ int lb[MAXBIN];
    int tid = threadIdx.x;
    for (int i = tid; i < NBIN; i += SORT_TPB) lh[i] = 0;
    __syncthreads();
    int s = blockIdx.x * W, e = min(E, s + W);
    for (int j = s + tid; j < e; j += SORT_TPB) atomicAdd(&lh[ei[E + j] >> 7], 1);
    __syncthreads();
    for (int i = tid; i < NBIN; i += SORT_TPB) {
        int h = lh[i];
        int base = 0;
        if (h) {
            base = atomicAdd(&binCnt[i], h);
            if (base + h > BINCAP) base = BINCAP - h;  // fault-safety clamp (never expected)
        }
        lb[i] = i * BINCAP + base;
    }
    __syncthreads();
    for (int i = tid; i < NBIN; i += SORT_TPB) lh[i] = 0;
    __syncthreads();
    for (int j = s + tid; j < e; j += SORT_TPB) {
        int d = ei[E + j];
        int b = d >> 7;
        int r = atomicAdd(&lh[b], 1);
        binned[lb[b] + r] = ((u32)ei[j] << 7) | (u32)(d & 127);
    }
}

// Padded CSR at fixed per-bin base b*CSRCAP: per-dst slots pc = (c+1 self) rounded
// up to 8. Region sentinel-filled (N) over the used length, then self + real edges
// overwrite. offs[d] = start, ends[d] = start + pc (exact mult-8 range).
__global__ __launch_bounds__(256) void k_bcsr(const u32* __restrict__ binned,
                                              const int* __restrict__ binCnt,
                                              int N, int* __restrict__ offs,
                                              int* __restrict__ ends,
                                              float* __restrict__ dinv,
                                              int* __restrict__ csr) {
    __shared__ int cnt[128];
    __shared__ int off[128];
    __shared__ int tot;
    __shared__ int fillEnd;
    int b = blockIdx.x;
    int tid = threadIdx.x;
    int dLo = b << 7;
    int nd = min(128, N - dLo);
    int bbase = b * BINCAP;
    int gCnt = min(binCnt[b], BINCAP);
    int pbase = b * CSRCAP;
    if (tid < 128) cnt[tid] = 0;
    __syncthreads();
    for (int j = tid; j < gCnt; j += 256) atomicAdd(&cnt[binned[bbase + j] & 127u], 1);
    __syncthreads();
    int c = (tid < 128) ? cnt[tid] : 0;
    int pc = (tid < 128) ? ((c + 8) & ~7) : 0;  // (c+1 self) rounded up to 8
    int lane = tid & 63;
    int isc = pc;
    for (int d = 1; d < 64; d <<= 1) { int o = __shfl_up(isc, d, 64); if (lane >= d) isc += o; }
    if (tid == 63) tot = isc;
    __syncthreads();
    int add = (tid >= 64 && tid < 128) ? tot : 0;
    if (tid < 128) off[tid] = add + isc - pc;
    if (tid == 127) fillEnd = add + isc;  // total padded length for this bin
    __syncthreads();
    // sentinel-fill used padded region only
    for (int j = tid; j < fillEnd; j += 256) csr[pbase + j] = N;
    __syncthreads();
    if (tid < nd) {
        offs[dLo + tid] = pbase + off[tid];
        ends[dLo + tid] = pbase + off[tid] + pc;
        dinv[dLo + tid] = rsqrtf((float)(c + 1));
        csr[pbase + off[tid] + c] = dLo + tid;  // self-loop entry
    }
    if (tid < 128) cnt[tid] = 0;
    __syncthreads();
    for (int j = tid; j < gCnt; j += 256) {
        u32 v = binned[bbase + j];
        int d7 = (int)(v & 127u);
        int r = atomicAdd(&cnt[d7], 1);
        csr[pbase + off[d7] + r] = (int)(v >> 7);
    }
}

// ---------- fused weight converts (W[K][M] row-major -> Wt[M][K] bf16) ----------
// wt2/wt3 k-dim permuted by pi (agg128 stores feature pi(p) at position p).
__global__ void k_wtall(const float* __restrict__ W1, const float* __restrict__ W2,
                        const float* __restrict__ W3, u16* __restrict__ wt1,
                        u16* __restrict__ wt2, u16* __restrict__ wt3) {
    int idx = blockIdx.x * 256 + threadIdx.x;
    if (idx < 16384) {
        int k = idx >> 7, m = idx & 127;
        wt1[m * 128 + k] = f2bf(W1[idx]);
    } else if (idx < 32768) {
        int i = idx - 16384, p = i >> 7, m = i & 127;
        wt2[m * 128 + p] = f2bf(W2[permP(p) * 128 + m]);
    } else if (idx < 40960) {
        int i = idx - 32768, p = i >> 6, m = i & 63;
        wt3[m * 128 + p] = f2bf(W3[permP(p) * 64 + m]);
    }
}

// ---------- GEMM: g8 = fp8((x @ W) * dinv[row] * 16); also zeroes sentinel row N --
template <int M, bool F32IN>
__global__ __launch_bounds__(256) void k_gemm(const void* __restrict__ xin,
                                              const u16* __restrict__ wt,
                                              const float* __restrict__ dinv,
                                              u8* __restrict__ g8, int N) {
    constexpr int K = 128;
    constexpr int LDK = 136;
    __shared__ u16 lwt[M * LDK];
    int tid = threadIdx.x;
    if (blockIdx.x == 0 && tid < M / 16)  // keep sentinel row zero for padded agg
        *(uint4*)(g8 + (size_t)N * M + (size_t)tid * 16) = make_uint4(0u, 0u, 0u, 0u);
    const uint4* wsrc = (const uint4*)wt;
#pragma unroll
    for (int c = tid; c < M * K / 8; c += 256) {
        int row = c >> 4, kc = c & 15;
        *(uint4*)&lwt[row * LDK + kc * 8] = wsrc[c];
    }
    __syncthreads();
    int lane = tid & 63, wv = tid >> 6;
    int node = blockIdx.x * 64 + wv * 16 + (lane & 15);
    int nodec = min(node, N - 1);
    int kr = (lane >> 4) * 8;
    f32x4 acc[M / 16];
#pragma unroll
    for (int t = 0; t < M / 16; t++) acc[t] = (f32x4){0.f, 0.f, 0.f, 0.f};
#pragma unroll
    for (int ks = 0; ks < 4; ks++) {
        short8 bfr;
        if (F32IN) {
            const float* xr = (const float*)xin + (size_t)nodec * K + ks * 32 + kr;
            float4 fa = *(const float4*)xr;
            float4 fb = *(const float4*)(xr + 4);
            bfr = (short8){(short)f2bf(fa.x), (short)f2bf(fa.y), (short)f2bf(fa.z),
                           (short)f2bf(fa.w), (short)f2bf(fb.x), (short)f2bf(fb.y),
                           (short)f2bf(fb.z), (short)f2bf(fb.w)};
        } else {
            bfr = *(const short8*)((const u16*)xin + (size_t)nodec * K + ks * 32 + kr);
        }
#pragma unroll
        for (int t = 0; t < M / 16; t++) {
            short8 afr = *(const short8*)&lwt[(t * 16 + (lane & 15)) * LDK + ks * 32 + kr];
            acc[t] = __builtin_amdgcn_mfma_f32_16x16x32_bf16(afr, bfr, acc[t], 0, 0, 0);
        }
    }
    if (node < N) {
        float dv16 = dinv[node] * 16.0f;
        int r0 = (lane >> 4) * 4;
#pragma unroll
        for (int t = 0; t < M / 16; t++) {
            u32 w = __builtin_amdgcn_cvt_pk_fp8_f32(acc[t][0] * dv16, acc[t][1] * dv16, 0, false);
            w = __builtin_amdgcn_cvt_pk_fp8_f32(acc[t][2] * dv16, acc[t][3] * dv16, w, true);
            *(u32*)(g8 + (size_t)node * M + t * 16 + r0) = w;
        }
    }
}

// ---------- aggregation via MFMA: TWO nodes per wave ----------
// R8/R9 counters: agg64 == agg128 time at half the bytes/loads; prefetch null ->
// bound by per-node window-trips x chain latency / wave concurrency. R10: pack 2
// adjacent nodes per wave. agg128 splits by C-COLUMNS (bsel routes k-groups 0-1
// -> cols 0-7 = node A, k-groups 2-3 -> cols 8-15 = node B): one MFMA aggregates
// 2 slots of each node. Exhausted node: pointer freezes (in-bounds re-read),
// indices cndmask'd to sentinel N (zero row). No per-lane masks, no tail.
__global__ __launch_bounds__(256) void k_agg128(const u8* __restrict__ g8,
                                                const int* __restrict__ offs,
                                                const int* __restrict__ ends,
                                                const int* __restrict__ csr,
                                                const float* __restrict__ dinv,
                                                const float* __restrict__ bias,
                                                u16* __restrict__ hout, int N) {
    int wp = (blockIdx.x * 256 + threadIdx.x) >> 6;  // one wave per node PAIR
    int widA = wp * 2;
    if (widA >= N) return;
    int widB = widA + 1;
    bool hasB = widB < N;
    int lane = threadIdx.x & 63;
    int q = lane >> 4;   // k-group: 0,1 -> node A slots; 2,3 -> node B slots
    int f = lane & 15;   // A-row: feature chunk (bytes f*8..f*8+7 of each row)
    int sA = offs[widA], eA = ends[widA];
    int sB = hasB ? offs[widB] : 0;
    int eB = hasB ? ends[widB] : 0;
    // bsel: byte b of k-group g feeds col n: n<8 needs g<2 & b==n; n>=8 needs g>=2 & b==n-8
    int nn = f & 7;
    bool on = (f < 8) ? (q < 2) : (q >= 2);
    uint2 bsel;
    bsel.x = (on && nn < 4) ? (0x38u << (8 * nn)) : 0u;       // fp8 e4m3 1.0 = 0x38
    bsel.y = (on && nn >= 4) ? (0x38u << (8 * (nn - 4))) : 0u;
    const u8* gf = g8 + f * 8;
    bool isA = (q < 2);
    int qm = q & 1;
    f32x4 ac0 = {0.f, 0.f, 0.f, 0.f}, ac1 = ac0, ac2 = ac0, ac3 = ac0;
    int jA = sA, jB = sB;
    while (jA < eA || jB < eB) {   // wave-uniform
        bool okA = jA < eA, okB = jB < eB;
        int base = isA ? jA : jB;
        bool ok = isA ? okA : okB;
        int i0 = csr[base + qm];        // frozen pointer stays in-bounds when !ok
        int i1 = csr[base + 2 + qm];
        int i2 = csr[base + 4 + qm];
        int i3 = csr[base + 6 + qm];
        if (!ok) { i0 = N; i1 = N; i2 = N; i3 = N; }  // sentinel -> zero row
        uint2 w0 = *(const uint2*)(gf + ((u32)i0 << 7));
        uint2 w1 = *(const uint2*)(gf + ((u32)i1 << 7));
        uint2 w2 = *(const uint2*)(gf + ((u32)i2 << 7));
        uint2 w3 = *(const uint2*)(gf + ((u32)i3 << 7));
        ac0 = mfma_fp8(w0, bsel, ac0);
        ac1 = mfma_fp8(w1, bsel, ac1);
        ac2 = mfma_fp8(w2, bsel, ac2);
        ac3 = mfma_fp8(w3, bsel, ac3);
        if (okA) jA += 8;
        if (okB) jB += 8;
    }
    f32x4 a = (ac0 + ac1) + (ac2 + ac3);
    // C layout: col = lane&15 (n<8 -> node A, n>=8 -> node B), row = fq*4+r = chunk
    int jn = lane & 15, fq = lane >> 4;
    int node = (jn < 8) ? widA : widB;
    if (node < N) {
        float sc = dinv[node] * 0.0625f;
        int bb = (jn & 7);
        u32 o0, o1;
        {
            float v0 = fmaxf(fmaf(a[0], sc, bias[(4 * fq + 0) * 8 + bb]), 0.f);
            float v1 = fmaxf(fmaf(a[1], sc, bias[(4 * fq + 1) * 8 + bb]), 0.f);
            o0 = (u32)f2bf(v0) | ((u32)f2bf(v1) << 16);
        }
        {
            float v2 = fmaxf(fmaf(a[2], sc, bias[(4 * fq + 2) * 8 + bb]), 0.f);
            float v3 = fmaxf(fmaf(a[3], sc, bias[(4 * fq + 3) * 8 + bb]), 0.f);
            o1 = (u32)f2bf(v2) | ((u32)f2bf(v3) << 16);
        }
        // permuted store: position p = fq*32 + bb*4 + r holds feature (4fq+r)*8+bb
        *(uint2*)&hout[(size_t)node * 128 + fq * 32 + bb * 4] = make_uint2(o0, o1);
    }
}

// ---------- layer-3 aggregation + log_softmax (F=64), TWO nodes per wave ----------
// Nodes split by C-ROWS: A-rows 0-7 gather node A, rows 8-15 node B (standard
// bsel; row index separates nodes). 4 slots/node per MFMA; no shfl combine.
__global__ __launch_bounds__(256) void k_agg64(const u8* __restrict__ g8,
                                               const int* __restrict__ offs,
                                               const int* __restrict__ ends,
                                               const int* __restrict__ csr,
                                               const float* __restrict__ dinv,
                                               const float* __restrict__ bias,
                                               float* __restrict__ out, int N) {
    __shared__ float sm[4][2][64];
    int wp = (blockIdx.x * 256 + threadIdx.x) >> 6;
    int widA = wp * 2;
    if (widA >= N) return;
    int widB = widA + 1;
    bool hasB = widB < N;
    int lane = threadIdx.x & 63;
    int wv = (int)(threadIdx.x >> 6);
    int q = lane >> 4;
    int f = lane & 15;
    bool isA = (f < 8);   // A-rows 0-7 -> node A, 8-15 -> node B
    int sA = offs[widA], eA = ends[widA];
    int sB = hasB ? offs[widB] : 0;
    int eB = hasB ? ends[widB] : 0;
    uint2 bsel;
    bsel.x = (f < 4) ? (0x38u << (8 * f)) : 0u;
    bsel.y = (f >= 4 && f < 8) ? (0x38u << (8 * (f - 4))) : 0u;
    const u8* gf = g8 + (f & 7) * 8;
    f32x4 ac0 = {0.f, 0.f, 0.f, 0.f}, ac1 = ac0;
    int jA = sA, jB = sB;
    while (jA < eA || jB < eB) {   // wave-uniform
        bool okA = jA < eA, okB = jB < eB;
        int base = isA ? jA : jB;
        bool ok = isA ? okA : okB;
        int i0 = csr[base + q];
        int i1 = csr[base + 4 + q];
        if (!ok) { i0 = N; i1 = N; }
        uint2 w0 = *(const uint2*)(gf + ((u32)i0 << 6));
        uint2 w1 = *(const uint2*)(gf + ((u32)i1 << 6));
        ac0 = mfma_fp8(w0, bsel, ac0);
        ac1 = mfma_fp8(w1, bsel, ac1);
        if (okA) jA += 8;
        if (okB) jB += 8;
    }
    f32x4 a = ac0 + ac1;
    // C rows 0-7 (fq 0,1) = node A chunks, rows 8-15 (fq 2,3) = node B chunks
    int jn = lane & 15, fq = lane >> 4;
    int half = fq >> 1;           // 0 = A, 1 = B
    int node = widA + half;
    bool act = (jn < 8) && (node < N);
    if (act) {
        float sc = dinv[node] * 0.0625f;
        int ch = (fq & 1);        // chunk base = ch*4 + r within the node
        float v0 = fmaf(a[0], sc, bias[(4 * ch + 0) * 8 + jn]);
        float v1 = fmaf(a[1], sc, bias[(4 * ch + 1) * 8 + jn]);
        float v2 = fmaf(a[2], sc, bias[(4 * ch + 2) * 8 + jn]);
        float v3 = fmaf(a[3], sc, bias[(4 * ch + 3) * 8 + jn]);
        // reduce over this node's 16 lanes: jn bits (xor 1,2,4) + fq low bit (xor 16)
        float m = fmaxf(fmaxf(v0, v1), fmaxf(v2, v3));
        m = fmaxf(m, __shfl_xor(m, 1, 64));
        m = fmaxf(m, __shfl_xor(m, 2, 64));
        m = fmaxf(m, __shfl_xor(m, 4, 64));
        m = fmaxf(m, __shfl_xor(m, 16, 64));
        float ss = __expf(v0 - m) + __expf(v1 - m) + __expf(v2 - m) + __expf(v3 - m);
        ss += __shfl_xor(ss, 1, 64);
        ss += __shfl_xor(ss, 2, 64);
        ss += __shfl_xor(ss, 4, 64);
        ss += __shfl_xor(ss, 16, 64);
        float lg = m + __logf(ss);
        sm[wv][half][(4 * ch + 0) * 8 + jn] = v0 - lg;
        sm[wv][half][(4 * ch + 1) * 8 + jn] = v1 - lg;
        sm[wv][half][(4 * ch + 2) * 8 + jn] = v2 - lg;
        sm[wv][half][(4 * ch + 3) * 8 + jn] = v3 - lg;
    }
    // same-wave LDS bounce: lanes 0-15 write node A, 16-31 write node B
    if (lane < 32) {
        int h = lane >> 4;
        int node2 = widA + h;
        if (node2 < N) {
            float4 ov = *(float4*)&sm[wv][h][(lane & 15) * 4];
            *(float4*)&out[(size_t)node2 * 64 + (lane & 15) * 4] = ov;
        }
    }
}

extern "C" void kernel_launch(void* const* d_in, const int* in_sizes, int n_in,
                              void* d_out, int out_size, void* d_ws, size_t ws_size,
                              hipStream_t stream) {
    const float* x  = (const float*)d_in[0];
    const int*   ei = (const int*)d_in[1];
    const float* W1 = (const float*)d_in[2];
    const float* b1 = (const float*)d_in[3];
    const float* W2 = (const float*)d_in[4];
    const float* b2 = (const float*)d_in[5];
    const float* W3 = (const float*)d_in[6];
    const float* b3 = (const float*)d_in[7];
    const int N = in_sizes[0] / 128;
    const int E = in_sizes[1] / 2;
    const int NBIN = (N + 127) >> 7;  // bins of 128 dsts

    char* ws = (char*)d_ws;
    size_t o = 0;
    auto alloc = [&](size_t bytes) -> char* {
        char* p = ws + o;
        o += (bytes + 255) & ~(size_t)255;
        return p;
    };
    int*   binCnt = (int*)alloc((size_t)MAXBIN * 4);
    float* dinv   = (float*)alloc((size_t)N * 4);
    int*   offs   = (int*)alloc((size_t)N * 4);
    int*   endsA  = (int*)alloc((size_t)N * 4);
    int*   csr    = (int*)alloc(((size_t)NBIN * CSRCAP + 64) * 4);
    u16*   wt1    = (u16*)alloc(128 * 128 * 2);
    u16*   wt2    = (u16*)alloc(128 * 128 * 2);
    u16*   wt3    = (u16*)alloc(64 * 128 * 2);
    u8*    g8     = (u8*)alloc(((size_t)N + 1) * 128);  // +1: zero sentinel row
    u16*   hbuf   = (u16*)alloc((size_t)N * 128 * 2);
    u32*   binned = (u32*)hbuf;  // alias (16MB <= 25.6MB): dead before first agg write
    float* outp   = (float*)d_out;

    hipMemsetAsync(binCnt, 0, (size_t)MAXBIN * 4, stream);
    int W256 = (E + 255) / 256;  // edges per block at 256 blocks
    k_bscatter<<<256, SORT_TPB, 0, stream>>>(ei, E, W256, binCnt, binned, NBIN);
    k_bcsr<<<NBIN, 256, 0, stream>>>(binned, binCnt, N, offs, endsA, dinv, csr);
    k_wtall<<<(40960 + 255) / 256, 256, 0, stream>>>(W1, W2, W3, wt1, wt2, wt3);

    int gG = (N + 63) / 64;                 // GEMM: 64 nodes/block
    int P  = (N + 1) / 2;                   // node pairs
    int gA = (P + 3) / 4;                   // agg: 1 wave per pair, 4 waves/block

    k_gemm<128, true ><<<gG, 256, 0, stream>>>(x,    wt1, dinv, g8, N);
    k_agg128<<<gA, 256, 0, stream>>>(g8, offs, endsA, csr, dinv, b1, hbuf, N);
    k_gemm<128, false><<<gG, 256, 0, stream>>>(hbuf, wt2, dinv, g8, N);
    k_agg128<<<gA, 256, 0, stream>>>(g8, offs, endsA, csr, dinv, b2, hbuf, N);
    k_gemm<64,  false><<<gG, 256, 0, stream>>>(hbuf, wt3, dinv, g8, N);
    k_agg64<<<gA, 256, 0, stream>>>(g8, offs, endsA, csr, dinv, b3, outp, N);
}